// Round 2
// baseline (14785.826 us; speedup 1.0000x reference)
//
#include <hip/hip_runtime.h>
#include <hip/hip_bf16.h>

#define DXc 256
#define DYc 32
#define Kc 4
#define Hc 128
#define LRf 0.1f
#define REGf 0.01f
#define TSTEPS 1000

// ---------------------------------------------------------------------------
// Setup kernel: derived weight matrices into workspace.
//   Wcat (256x256) = [ e_w1[:256] | P ]  where P = s_xw @ A0,  A0 = tr1w[0:128]
//   WyT  (128x32)  = e_w1[256:288]^T ;  MT (128x32) = (s_yw @ A1)^T
//   d0   (4x128)   = temb[t]@A2 + th[t]@A3 + s_yb@A1 + s_xb@A0 + tr1b
// ---------------------------------------------------------------------------
__global__ __launch_bounds__(256) void setup_kernel(
    const float* __restrict__ e_w1, const float* __restrict__ s_xw,
    const float* __restrict__ s_yw, const float* __restrict__ s_temb,
    const float* __restrict__ s_t1w, const float* __restrict__ s_t1b,
    const float* __restrict__ s_t2w, const float* __restrict__ s_t2b,
    const float* __restrict__ tr1w, const float* __restrict__ tr1b,
    const float* __restrict__ s_xb, const float* __restrict__ s_yb,
    float* __restrict__ Wcat, float* __restrict__ WyT,
    float* __restrict__ MT, float* __restrict__ d0)
{
    const int b = blockIdx.x;
    const int t = threadIdx.x;
    if (b < 64) {
        // P rows 4b..4b+3 and copy of E rows into Wcat
        #pragma unroll
        for (int i = 0; i < 2; ++i) {
            int idx = t + 256 * i;              // 0..511
            int k = 4 * b + (idx >> 7);
            int c = idx & 127;
            float acc = 0.f;
            for (int h = 0; h < 128; ++h)
                acc += s_xw[k * 128 + h] * tr1w[h * 128 + c];
            Wcat[k * 256 + 128 + c] = acc;
            Wcat[k * 256 + c] = e_w1[k * 128 + c];
        }
    } else if (b == 64) {
        // MT[h][d] = (s_yw @ A1)[d][h]
        #pragma unroll
        for (int i = 0; i < 16; ++i) {
            int idx = t + 256 * i;              // 0..4095
            int d = idx >> 7, c = idx & 127;
            float acc = 0.f;
            for (int h = 0; h < 128; ++h)
                acc += s_yw[d * 128 + h] * tr1w[(128 + h) * 128 + c];
            MT[c * 32 + d] = acc;
        }
    } else if (b == 65) {
        // WyT
        #pragma unroll
        for (int i = 0; i < 16; ++i) {
            int idx = t + 256 * i;
            int d = idx >> 7, c = idx & 127;
            WyT[c * 32 + d] = e_w1[(DXc + d) * 128 + c];
        }
    } else {
        // b == 66: th table then d0 table
        __shared__ float thS[4][128];
        #pragma unroll
        for (int i = 0; i < 2; ++i) {
            int idx = t + 256 * i;              // 0..511
            int tt = idx >> 7, c = idx & 127;
            float tau = (float)tt / (float)TSTEPS;
            if (tau < 1e-6f) tau = 1e-6f;
            float acc = s_t2b[c];
            for (int h = 0; h < 128; ++h) {
                float aa = tau * s_t1w[h] + s_t1b[h];
                float s = 1.f / (1.f + expf(-aa));
                acc += aa * s * s_t2w[h * 128 + c];
            }
            thS[tt][c] = acc;
        }
        __syncthreads();
        #pragma unroll
        for (int i = 0; i < 2; ++i) {
            int idx = t + 256 * i;
            int tt = idx >> 7, c = idx & 127;
            float acc = tr1b[c];
            for (int h = 0; h < 128; ++h) {
                acc += s_temb[tt * 128 + h] * tr1w[(256 + h) * 128 + c];
                acc += thS[tt][h]           * tr1w[(384 + h) * 128 + c];
                acc += s_yb[h]              * tr1w[(128 + h) * 128 + c];
                acc += s_xb[h]              * tr1w[h * 128 + c];
            }
            d0[tt * 128 + c] = acc;
        }
    }
}

// ---------------------------------------------------------------------------
// Row precompute: hxe = x@E + e_b1 ; cb = x@P + d0[t]
// Output in BLOCK-TRANSPOSED layout: hxeB[blk][h][64] with blk = row/64,
// so the iterate kernel's lane-r loads are 256B coalesced and each wave's
// working set (64KB) is a contiguous L2-resident chunk.
// ---------------------------------------------------------------------------
__global__ __launch_bounds__(256) void rowpre_kernel(
    const float* __restrict__ x, const int* __restrict__ tin,
    const float* __restrict__ Wcat, const float* __restrict__ e_b1,
    const float* __restrict__ d0,
    float* __restrict__ hxeB, float* __restrict__ cbB)
{
    __shared__ float XsT[64][68];
    __shared__ float T[128][65];
    __shared__ int tS[64];
    __shared__ float eb1S[128];

    const int t = threadIdx.x;
    const int r0 = blockIdx.x * 64;
    if (t < 64) { int tv = tin[r0 + t]; tS[t] = tv > 0 ? tv : 0; }
    if (t < 128) eb1S[t] = e_b1[t];

    const int rg = t >> 4;       // 0..15
    const int cg = t & 15;       // 0..15
    const int R = rg << 2;

    float acc[4][16];
    #pragma unroll
    for (int rr = 0; rr < 4; ++rr)
        #pragma unroll
        for (int cc = 0; cc < 16; ++cc) acc[rr][cc] = 0.f;

    for (int kc = 0; kc < 4; ++kc) {
        __syncthreads();
        #pragma unroll
        for (int i = 0; i < 4; ++i) {
            int lin = t + 256 * i;           // 0..1023
            int rr = lin >> 4;               // 0..63
            int c4 = (lin & 15) << 2;        // 0..60
            float4 v = *(const float4*)&x[(size_t)(r0 + rr) * 256 + kc * 64 + c4];
            XsT[c4 + 0][rr] = v.x;
            XsT[c4 + 1][rr] = v.y;
            XsT[c4 + 2][rr] = v.z;
            XsT[c4 + 3][rr] = v.w;
        }
        __syncthreads();
        #pragma unroll 2
        for (int k = 0; k < 64; ++k) {
            float av[4];
            #pragma unroll
            for (int rr = 0; rr < 4; ++rr) av[rr] = XsT[k][R + rr];
            const float* wrow = &Wcat[(size_t)(kc * 64 + k) * 256 + cg];
            #pragma unroll
            for (int cc = 0; cc < 16; ++cc) {
                float bv = wrow[cc * 16];
                #pragma unroll
                for (int rr = 0; rr < 4; ++rr) acc[rr][cc] += av[rr] * bv;
            }
        }
    }
    // hxe: cols = cg + 16*cc for cc<8 -> LDS transpose -> coalesced store
    #pragma unroll
    for (int cc = 0; cc < 8; ++cc) {
        int c = cg + (cc << 4);
        #pragma unroll
        for (int rr = 0; rr < 4; ++rr)
            T[c][R + rr] = acc[rr][cc] + eb1S[c];
    }
    __syncthreads();
    {
        float* outp = hxeB + (size_t)blockIdx.x * 8192;
        #pragma unroll
        for (int i = 0; i < 32; ++i) {
            int idx = t + (i << 8);          // 0..8191 ; idx = h*64 + j
            outp[idx] = T[idx >> 6][idx & 63];
        }
    }
    __syncthreads();
    // cb
    #pragma unroll
    for (int cc = 8; cc < 16; ++cc) {
        int c = cg + ((cc - 8) << 4);
        #pragma unroll
        for (int rr = 0; rr < 4; ++rr)
            T[c][R + rr] = acc[rr][cc] + d0[tS[R + rr] * 128 + c];
    }
    __syncthreads();
    {
        float* outp = cbB + (size_t)blockIdx.x * 8192;
        #pragma unroll
        for (int i = 0; i < 32; ++i) {
            int idx = t + (i << 8);
            outp[idx] = T[idx >> 6][idx & 63];
        }
    }
}

// ---------------------------------------------------------------------------
// Iterate kernel: ONE THREAD = ONE ROW. 20 GD steps, all state in VGPRs,
// weights via wave-uniform (scalar) loads, no barriers in the step loop.
//   fwd : stream h: z1,a (64 FMA) -> silu/logits -> z2[c] += h1*e_w2[h][:]
//   bwd : recompute z1,a per h; dh1_h = dot(dz2[128], e_w2[h][:]);
//         dy += da_h*MT[h][:] + relu'(z1_h)*dh1_h*WyT[h][:]
// ---------------------------------------------------------------------------
__global__ __launch_bounds__(256, 2) void iterate_kernel(
    const float* __restrict__ hxeB, const float* __restrict__ cbB,
    const float* __restrict__ WyT, const float* __restrict__ MT,
    const float* __restrict__ e_w2, const float* __restrict__ e_w3,
    const float* __restrict__ tr2w, const float* __restrict__ tr2b,
    const float* __restrict__ e_b2, const int* __restrict__ tin,
    const int* __restrict__ stepsPtr, float* __restrict__ yout)
{
    __shared__ float ew3S[4 * 129];          // e_w3^T, padded row 129 (bank-safe)
    const int t = threadIdx.x;
    for (int i = t; i < 512; i += 256) {
        int h = i >> 2, k = i & 3;
        ew3S[k * 129 + h] = e_w3[i];
    }

    const int r = blockIdx.x * 256 + t;
    const size_t base = ((size_t)(r >> 6)) * 8192 + (size_t)(r & 63);
    int tv = tin[r];
    const int tcv = tv > 0 ? tv : 0;
    const float vd = tv >= 0 ? 1.0f : 0.0f;
    const int nsteps = stepsPtr[0];
    const float tb0 = tr2b[0], tb1 = tr2b[1], tb2 = tr2b[2], tb3 = tr2b[3];

    float y[32];
    #pragma unroll
    for (int d = 0; d < 32; ++d) y[d] = 0.f;

    __syncthreads();

    for (int step = 0; step < nsteps; ++step) {
        // ---------------- forward ----------------
        float z2[128];
        #pragma unroll
        for (int c = 0; c < 128; ++c) z2[c] = e_b2[c];
        float lg0 = tb0, lg1 = tb1, lg2 = tb2, lg3 = tb3;

        float hx = hxeB[base];
        float cbv = cbB[base];
        for (int h = 0; h < 128; ++h) {
            const float hx_c = hx, cb_c = cbv;
            const int hn = h < 127 ? h + 1 : 127;      // rotate-prefetch
            hx  = hxeB[base + (size_t)hn * 64];
            cbv = cbB[base + (size_t)hn * 64];

            const float* __restrict__ wy = WyT + (h << 5);
            const float* __restrict__ mt = MT  + (h << 5);
            float z1 = hx_c, a = cb_c;
            #pragma unroll
            for (int d = 0; d < 32; ++d) {
                z1 += y[d] * wy[d];
                a  += y[d] * mt[d];
            }
            const float h1 = z1 > 0.f ? z1 : 0.f;
            const float s = 1.0f / (1.0f + __expf(-a));
            const float u = a * s;
            lg0 += u * tr2w[(h << 2) + 0];
            lg1 += u * tr2w[(h << 2) + 1];
            lg2 += u * tr2w[(h << 2) + 2];
            lg3 += u * tr2w[(h << 2) + 3];

            const float* __restrict__ w2 = e_w2 + (h << 7);
            #pragma unroll
            for (int c = 0; c < 128; ++c) z2[c] += h1 * w2[c];
        }

        // ---------------- softmax grad ----------------
        const float mx = fmaxf(fmaxf(lg0, lg1), fmaxf(lg2, lg3));
        const float e0 = __expf(lg0 - mx), e1 = __expf(lg1 - mx);
        const float e2 = __expf(lg2 - mx), e3 = __expf(lg3 - mx);
        const float inv = 1.0f / (e0 + e1 + e2 + e3);
        const float dl0 = (e0 * inv - (tcv == 0 ? 1.f : 0.f)) * vd;
        const float dl1 = (e1 * inv - (tcv == 1 ? 1.f : 0.f)) * vd;
        const float dl2 = (e2 * inv - (tcv == 2 ? 1.f : 0.f)) * vd;
        const float dl3 = (e3 * inv - (tcv == 3 ? 1.f : 0.f)) * vd;

        // ---------------- dz2 (in place) ----------------
        #pragma unroll
        for (int c = 0; c < 128; ++c) {
            const float gv = ew3S[tcv * 129 + c];
            z2[c] = z2[c] > 0.f ? gv : 0.f;
        }

        // ---------------- backward ----------------
        float dy[32];
        #pragma unroll
        for (int d = 0; d < 32; ++d) dy[d] = 0.f;

        hx  = hxeB[base];
        cbv = cbB[base];
        for (int h = 0; h < 128; ++h) {
            const float hx_c = hx, cb_c = cbv;
            const int hn = h < 127 ? h + 1 : 127;
            hx  = hxeB[base + (size_t)hn * 64];
            cbv = cbB[base + (size_t)hn * 64];

            const float* __restrict__ wy = WyT + (h << 5);
            const float* __restrict__ mt = MT  + (h << 5);
            float z1 = hx_c, a = cb_c;
            #pragma unroll
            for (int d = 0; d < 32; ++d) {
                z1 += y[d] * wy[d];
                a  += y[d] * mt[d];
            }
            const float s = 1.0f / (1.0f + __expf(-a));
            const float g = dl0 * tr2w[(h << 2) + 0] + dl1 * tr2w[(h << 2) + 1]
                          + dl2 * tr2w[(h << 2) + 2] + dl3 * tr2w[(h << 2) + 3];
            const float da = g * (s * (1.0f + a * (1.0f - s)));   // silu'

            const float* __restrict__ w2 = e_w2 + (h << 7);
            float t0 = 0.f, t1 = 0.f, t2 = 0.f, t3 = 0.f;
            float t4 = 0.f, t5 = 0.f, t6 = 0.f, t7 = 0.f;
            #pragma unroll
            for (int c = 0; c < 128; c += 8) {
                t0 += z2[c + 0] * w2[c + 0];
                t1 += z2[c + 1] * w2[c + 1];
                t2 += z2[c + 2] * w2[c + 2];
                t3 += z2[c + 3] * w2[c + 3];
                t4 += z2[c + 4] * w2[c + 4];
                t5 += z2[c + 5] * w2[c + 5];
                t6 += z2[c + 6] * w2[c + 6];
                t7 += z2[c + 7] * w2[c + 7];
            }
            float dh1 = ((t0 + t1) + (t2 + t3)) + ((t4 + t5) + (t6 + t7));
            dh1 = z1 > 0.f ? dh1 : 0.f;
            #pragma unroll
            for (int d = 0; d < 32; ++d)
                dy[d] += da * mt[d] + dh1 * wy[d];
        }

        // ---------------- y update ----------------
        #pragma unroll
        for (int d = 0; d < 32; ++d)
            y[d] -= LRf * (dy[d] + 2.0f * REGf * y[d]);
    }

    // ---------------- write out ----------------
    #pragma unroll
    for (int d = 0; d < 32; d += 4) {
        float4 o;
        o.x = y[d + 0]; o.y = y[d + 1]; o.z = y[d + 2]; o.w = y[d + 3];
        *(float4*)&yout[(size_t)r * 32 + d] = o;
    }
}

// ---------------------------------------------------------------------------
extern "C" void kernel_launch(void* const* d_in, const int* in_sizes, int n_in,
                              void* d_out, int out_size, void* d_ws, size_t ws_size,
                              hipStream_t stream)
{
    const float* x      = (const float*)d_in[0];
    const int*   tin    = (const int*)d_in[1];
    const float* e_w1   = (const float*)d_in[2];
    const float* e_b1   = (const float*)d_in[3];
    const float* e_w2   = (const float*)d_in[4];
    const float* e_b2   = (const float*)d_in[5];
    const float* e_w3   = (const float*)d_in[6];
    const float* s_xw   = (const float*)d_in[8];
    const float* s_xb   = (const float*)d_in[9];
    const float* s_yw   = (const float*)d_in[10];
    const float* s_yb   = (const float*)d_in[11];
    const float* s_temb = (const float*)d_in[12];
    const float* s_t1w  = (const float*)d_in[13];
    const float* s_t1b  = (const float*)d_in[14];
    const float* s_t2w  = (const float*)d_in[15];
    const float* s_t2b  = (const float*)d_in[16];
    const float* tr1w   = (const float*)d_in[17];
    const float* tr1b   = (const float*)d_in[18];
    const float* tr2w   = (const float*)d_in[19];
    const float* tr2b   = (const float*)d_in[20];
    const int*   steps  = (const int*)d_in[21];

    const int B = in_sizes[0] / DXc;

    float* ws    = (float*)d_ws;
    float* hxeB  = ws;
    float* cbB   = hxeB + (size_t)B * 128;
    float* Wcat  = cbB  + (size_t)B * 128;
    float* WyT   = Wcat + 256 * 256;
    float* MT    = WyT  + 128 * 32;
    float* d0    = MT   + 128 * 32;

    setup_kernel<<<67, 256, 0, stream>>>(e_w1, s_xw, s_yw, s_temb, s_t1w, s_t1b,
                                         s_t2w, s_t2b, tr1w, tr1b, s_xb, s_yb,
                                         Wcat, WyT, MT, d0);
    rowpre_kernel<<<B / 64, 256, 0, stream>>>(x, tin, Wcat, e_b1, d0, hxeB, cbB);
    iterate_kernel<<<B / 256, 256, 0, stream>>>(hxeB, cbB, WyT, MT, e_w2, e_w3,
                                                tr2w, tr2b, e_b2, tin, steps,
                                                (float*)d_out);
}

// Round 3
// 14741.199 us; speedup vs baseline: 1.0030x; 1.0030x over previous
//
#include <hip/hip_runtime.h>
#include <hip/hip_bf16.h>

#define DXc 256
#define DYc 32
#define Kc 4
#define Hc 128
#define LRf 0.1f
#define REGf 0.01f
#define TSTEPS 1000

// ---------------------------------------------------------------------------
// Setup kernel: derived weight matrices into workspace.
//   Wcat (256x256) = [ e_w1[:256] | P ]  where P = s_xw @ A0,  A0 = tr1w[0:128]
//   WyT  (128x32)  = e_w1[256:288]^T ;  MT (128x32) = (s_yw @ A1)^T
//   d0   (4x128)   = temb[t]@A2 + th[t]@A3 + s_yb@A1 + s_xb@A0 + tr1b
// ---------------------------------------------------------------------------
__global__ __launch_bounds__(256) void setup_kernel(
    const float* __restrict__ e_w1, const float* __restrict__ s_xw,
    const float* __restrict__ s_yw, const float* __restrict__ s_temb,
    const float* __restrict__ s_t1w, const float* __restrict__ s_t1b,
    const float* __restrict__ s_t2w, const float* __restrict__ s_t2b,
    const float* __restrict__ tr1w, const float* __restrict__ tr1b,
    const float* __restrict__ s_xb, const float* __restrict__ s_yb,
    float* __restrict__ Wcat, float* __restrict__ WyT,
    float* __restrict__ MT, float* __restrict__ d0)
{
    const int b = blockIdx.x;
    const int t = threadIdx.x;
    if (b < 64) {
        #pragma unroll
        for (int i = 0; i < 2; ++i) {
            int idx = t + 256 * i;              // 0..511
            int k = 4 * b + (idx >> 7);
            int c = idx & 127;
            float acc = 0.f;
            for (int h = 0; h < 128; ++h)
                acc += s_xw[k * 128 + h] * tr1w[h * 128 + c];
            Wcat[k * 256 + 128 + c] = acc;
            Wcat[k * 256 + c] = e_w1[k * 128 + c];
        }
    } else if (b == 64) {
        // MT[h][d] = (s_yw @ A1)[d][h]
        #pragma unroll
        for (int i = 0; i < 16; ++i) {
            int idx = t + 256 * i;              // 0..4095
            int d = idx >> 7, c = idx & 127;
            float acc = 0.f;
            for (int h = 0; h < 128; ++h)
                acc += s_yw[d * 128 + h] * tr1w[(128 + h) * 128 + c];
            MT[c * 32 + d] = acc;
        }
    } else if (b == 65) {
        // WyT
        #pragma unroll
        for (int i = 0; i < 16; ++i) {
            int idx = t + 256 * i;
            int d = idx >> 7, c = idx & 127;
            WyT[c * 32 + d] = e_w1[(DXc + d) * 128 + c];
        }
    } else {
        // b == 66: th table then d0 table
        __shared__ float thS[4][128];
        #pragma unroll
        for (int i = 0; i < 2; ++i) {
            int idx = t + 256 * i;              // 0..511
            int tt = idx >> 7, c = idx & 127;
            float tau = (float)tt / (float)TSTEPS;
            if (tau < 1e-6f) tau = 1e-6f;
            float acc = s_t2b[c];
            for (int h = 0; h < 128; ++h) {
                float aa = tau * s_t1w[h] + s_t1b[h];
                float s = 1.f / (1.f + expf(-aa));
                acc += aa * s * s_t2w[h * 128 + c];
            }
            thS[tt][c] = acc;
        }
        __syncthreads();
        #pragma unroll
        for (int i = 0; i < 2; ++i) {
            int idx = t + 256 * i;
            int tt = idx >> 7, c = idx & 127;
            float acc = tr1b[c];
            for (int h = 0; h < 128; ++h) {
                acc += s_temb[tt * 128 + h] * tr1w[(256 + h) * 128 + c];
                acc += thS[tt][h]           * tr1w[(384 + h) * 128 + c];
                acc += s_yb[h]              * tr1w[(128 + h) * 128 + c];
                acc += s_xb[h]              * tr1w[h * 128 + c];
            }
            d0[tt * 128 + c] = acc;
        }
    }
}

// ---------------------------------------------------------------------------
// Row precompute: hxe = x@E + e_b1 ; cb = x@P + d0[t]
// Output BLOCK-TRANSPOSED: hxeB[blk][h][64], blk = row/64 -> coalesced,
// L2/L3-friendly lane loads in the iterate kernel.
// ---------------------------------------------------------------------------
__global__ __launch_bounds__(256) void rowpre_kernel(
    const float* __restrict__ x, const int* __restrict__ tin,
    const float* __restrict__ Wcat, const float* __restrict__ e_b1,
    const float* __restrict__ d0,
    float* __restrict__ hxeB, float* __restrict__ cbB)
{
    __shared__ float XsT[64][68];
    __shared__ float T[128][65];
    __shared__ int tS[64];
    __shared__ float eb1S[128];

    const int t = threadIdx.x;
    const int r0 = blockIdx.x * 64;
    if (t < 64) { int tv = tin[r0 + t]; tS[t] = tv > 0 ? tv : 0; }
    if (t < 128) eb1S[t] = e_b1[t];

    const int rg = t >> 4;       // 0..15
    const int cg = t & 15;       // 0..15
    const int R = rg << 2;

    float acc[4][16];
    #pragma unroll
    for (int rr = 0; rr < 4; ++rr)
        #pragma unroll
        for (int cc = 0; cc < 16; ++cc) acc[rr][cc] = 0.f;

    for (int kc = 0; kc < 4; ++kc) {
        __syncthreads();
        #pragma unroll
        for (int i = 0; i < 4; ++i) {
            int lin = t + 256 * i;           // 0..1023
            int rr = lin >> 4;               // 0..63
            int c4 = (lin & 15) << 2;        // 0..60
            float4 v = *(const float4*)&x[(size_t)(r0 + rr) * 256 + kc * 64 + c4];
            XsT[c4 + 0][rr] = v.x;
            XsT[c4 + 1][rr] = v.y;
            XsT[c4 + 2][rr] = v.z;
            XsT[c4 + 3][rr] = v.w;
        }
        __syncthreads();
        #pragma unroll 2
        for (int k = 0; k < 64; ++k) {
            float av[4];
            #pragma unroll
            for (int rr = 0; rr < 4; ++rr) av[rr] = XsT[k][R + rr];
            const float* wrow = &Wcat[(size_t)(kc * 64 + k) * 256 + cg];
            #pragma unroll
            for (int cc = 0; cc < 16; ++cc) {
                float bv = wrow[cc * 16];
                #pragma unroll
                for (int rr = 0; rr < 4; ++rr) acc[rr][cc] += av[rr] * bv;
            }
        }
    }
    #pragma unroll
    for (int cc = 0; cc < 8; ++cc) {
        int c = cg + (cc << 4);
        #pragma unroll
        for (int rr = 0; rr < 4; ++rr)
            T[c][R + rr] = acc[rr][cc] + eb1S[c];
    }
    __syncthreads();
    {
        float* outp = hxeB + (size_t)blockIdx.x * 8192;
        #pragma unroll
        for (int i = 0; i < 32; ++i) {
            int idx = t + (i << 8);          // idx = h*64 + j
            outp[idx] = T[idx >> 6][idx & 63];
        }
    }
    __syncthreads();
    #pragma unroll
    for (int cc = 8; cc < 16; ++cc) {
        int c = cg + ((cc - 8) << 4);
        #pragma unroll
        for (int rr = 0; rr < 4; ++rr)
            T[c][R + rr] = acc[rr][cc] + d0[tS[R + rr] * 128 + c];
    }
    __syncthreads();
    {
        float* outp = cbB + (size_t)blockIdx.x * 8192;
        #pragma unroll
        for (int i = 0; i < 32; ++i) {
            int idx = t + (i << 8);
            outp[idx] = T[idx >> 6][idx & 63];
        }
    }
}

// ---------------------------------------------------------------------------
// Iterate kernel: ONE THREAD = ONE ROW, all state in VGPRs.
// Grid is 512 blocks -> max 2 blocks/CU structurally, so we pin the
// allocator to exactly 2 waves/EU (256-VGPR budget): amdgpu_waves_per_eu(2,2).
// R2's failure: launch_bounds floor let the allocator target 4 waves/EU and
// spill z2[128] to scratch (3.8 GB HBM traffic). This pin removes the spill.
// ---------------------------------------------------------------------------
__global__ __attribute__((amdgpu_flat_work_group_size(256, 256),
                          amdgpu_waves_per_eu(2, 2)))
void iterate_kernel(
    const float* __restrict__ hxeB, const float* __restrict__ cbB,
    const float* __restrict__ WyT, const float* __restrict__ MT,
    const float* __restrict__ e_w2, const float* __restrict__ e_w3,
    const float* __restrict__ tr2w, const float* __restrict__ tr2b,
    const float* __restrict__ e_b2, const int* __restrict__ tin,
    const int* __restrict__ stepsPtr, float* __restrict__ yout)
{
    __shared__ float ew3S[4 * 132];          // e_w3^T, pad 132: tc*132+c -> distinct banks
    const int t = threadIdx.x;
    for (int i = t; i < 512; i += 256) {
        int h = i >> 2, k = i & 3;
        ew3S[k * 132 + h] = e_w3[i];
    }

    const int r = blockIdx.x * 256 + t;
    const size_t base = ((size_t)(r >> 6)) * 8192 + (size_t)(r & 63);
    const float* __restrict__ hxp = hxeB + base;
    const float* __restrict__ cbp = cbB + base;
    int tv = tin[r];
    const int tcv = tv > 0 ? tv : 0;
    const float vd = tv >= 0 ? 1.0f : 0.0f;
    const int nsteps = stepsPtr[0];
    const float tb0 = tr2b[0], tb1 = tr2b[1], tb2 = tr2b[2], tb3 = tr2b[3];
    const float* __restrict__ ew3row = ew3S + tcv * 132;

    float y[32];
    #pragma unroll
    for (int d = 0; d < 32; ++d) y[d] = 0.f;

    __syncthreads();

    for (int step = 0; step < nsteps; ++step) {
        // ---------------- forward ----------------
        float z2[128];
        #pragma unroll
        for (int c = 0; c < 128; ++c) z2[c] = e_b2[c];
        float lg0 = tb0, lg1 = tb1, lg2 = tb2, lg3 = tb3;

        float hx0 = hxp[0],  cb0 = cbp[0];
        float hx1 = hxp[64], cb1 = cbp[64];
        #pragma unroll 1
        for (int h = 0; h < 128; ++h) {
            const float hx_c = hx0, cb_c = cb0;
            hx0 = hx1; cb0 = cb1;
            const int hn = h + 2 < 128 ? h + 2 : 127;      // depth-2 prefetch
            hx1 = hxp[(size_t)hn * 64];
            cb1 = cbp[(size_t)hn * 64];

            const float* __restrict__ wy = WyT + (h << 5);
            const float* __restrict__ mt = MT  + (h << 5);
            float z1 = hx_c, a = cb_c;
            #pragma unroll
            for (int d = 0; d < 32; ++d) {
                z1 += y[d] * wy[d];
                a  += y[d] * mt[d];
            }
            const float h1 = z1 > 0.f ? z1 : 0.f;
            const float s = 1.0f / (1.0f + __expf(-a));
            const float u = a * s;
            lg0 += u * tr2w[(h << 2) + 0];
            lg1 += u * tr2w[(h << 2) + 1];
            lg2 += u * tr2w[(h << 2) + 2];
            lg3 += u * tr2w[(h << 2) + 3];

            const float* __restrict__ w2 = e_w2 + (h << 7);
            #pragma unroll
            for (int c = 0; c < 128; ++c) z2[c] += h1 * w2[c];
        }

        // ---------------- softmax grad ----------------
        const float mx = fmaxf(fmaxf(lg0, lg1), fmaxf(lg2, lg3));
        const float e0 = __expf(lg0 - mx), e1 = __expf(lg1 - mx);
        const float e2 = __expf(lg2 - mx), e3 = __expf(lg3 - mx);
        const float inv = 1.0f / (e0 + e1 + e2 + e3);
        const float dl0 = (e0 * inv - (tcv == 0 ? 1.f : 0.f)) * vd;
        const float dl1 = (e1 * inv - (tcv == 1 ? 1.f : 0.f)) * vd;
        const float dl2 = (e2 * inv - (tcv == 2 ? 1.f : 0.f)) * vd;
        const float dl3 = (e3 * inv - (tcv == 3 ? 1.f : 0.f)) * vd;

        // ---------------- dz2 (in place) ----------------
        #pragma unroll
        for (int c = 0; c < 128; ++c) {
            const float gv = ew3row[c];
            z2[c] = z2[c] > 0.f ? gv : 0.f;
        }

        // ---------------- backward ----------------
        float dy[32];
        #pragma unroll
        for (int d = 0; d < 32; ++d) dy[d] = 0.f;

        hx0 = hxp[0];  cb0 = cbp[0];
        hx1 = hxp[64]; cb1 = cbp[64];
        #pragma unroll 1
        for (int h = 0; h < 128; ++h) {
            const float hx_c = hx0, cb_c = cb0;
            hx0 = hx1; cb0 = cb1;
            const int hn = h + 2 < 128 ? h + 2 : 127;
            hx1 = hxp[(size_t)hn * 64];
            cb1 = cbp[(size_t)hn * 64];

            const float* __restrict__ wy = WyT + (h << 5);
            const float* __restrict__ mt = MT  + (h << 5);
            float z1 = hx_c, a = cb_c;
            #pragma unroll
            for (int d = 0; d < 32; ++d) {
                z1 += y[d] * wy[d];
                a  += y[d] * mt[d];
            }
            const float s = 1.0f / (1.0f + __expf(-a));
            const float g = dl0 * tr2w[(h << 2) + 0] + dl1 * tr2w[(h << 2) + 1]
                          + dl2 * tr2w[(h << 2) + 2] + dl3 * tr2w[(h << 2) + 3];
            const float da = g * (s * (1.0f + a * (1.0f - s)));   // silu'

            const float* __restrict__ w2 = e_w2 + (h << 7);
            float t0 = 0.f, t1 = 0.f, t2 = 0.f, t3 = 0.f;
            float t4 = 0.f, t5 = 0.f, t6 = 0.f, t7 = 0.f;
            #pragma unroll
            for (int c = 0; c < 128; c += 8) {
                t0 += z2[c + 0] * w2[c + 0];
                t1 += z2[c + 1] * w2[c + 1];
                t2 += z2[c + 2] * w2[c + 2];
                t3 += z2[c + 3] * w2[c + 3];
                t4 += z2[c + 4] * w2[c + 4];
                t5 += z2[c + 5] * w2[c + 5];
                t6 += z2[c + 6] * w2[c + 6];
                t7 += z2[c + 7] * w2[c + 7];
            }
            float dh1 = ((t0 + t1) + (t2 + t3)) + ((t4 + t5) + (t6 + t7));
            dh1 = z1 > 0.f ? dh1 : 0.f;
            #pragma unroll
            for (int d = 0; d < 32; ++d)
                dy[d] += da * mt[d] + dh1 * wy[d];
        }

        // ---------------- y update ----------------
        #pragma unroll
        for (int d = 0; d < 32; ++d)
            y[d] -= LRf * (dy[d] + 2.0f * REGf * y[d]);
    }

    // ---------------- write out ----------------
    #pragma unroll
    for (int d = 0; d < 32; d += 4) {
        float4 o;
        o.x = y[d + 0]; o.y = y[d + 1]; o.z = y[d + 2]; o.w = y[d + 3];
        *(float4*)&yout[(size_t)r * 32 + d] = o;
    }
}

// ---------------------------------------------------------------------------
extern "C" void kernel_launch(void* const* d_in, const int* in_sizes, int n_in,
                              void* d_out, int out_size, void* d_ws, size_t ws_size,
                              hipStream_t stream)
{
    const float* x      = (const float*)d_in[0];
    const int*   tin    = (const int*)d_in[1];
    const float* e_w1   = (const float*)d_in[2];
    const float* e_b1   = (const float*)d_in[3];
    const float* e_w2   = (const float*)d_in[4];
    const float* e_b2   = (const float*)d_in[5];
    const float* e_w3   = (const float*)d_in[6];
    const float* s_xw   = (const float*)d_in[8];
    const float* s_xb   = (const float*)d_in[9];
    const float* s_yw   = (const float*)d_in[10];
    const float* s_yb   = (const float*)d_in[11];
    const float* s_temb = (const float*)d_in[12];
    const float* s_t1w  = (const float*)d_in[13];
    const float* s_t1b  = (const float*)d_in[14];
    const float* s_t2w  = (const float*)d_in[15];
    const float* s_t2b  = (const float*)d_in[16];
    const float* tr1w   = (const float*)d_in[17];
    const float* tr1b   = (const float*)d_in[18];
    const float* tr2w   = (const float*)d_in[19];
    const float* tr2b   = (const float*)d_in[20];
    const int*   steps  = (const int*)d_in[21];

    const int B = in_sizes[0] / DXc;

    float* ws    = (float*)d_ws;
    float* hxeB  = ws;
    float* cbB   = hxeB + (size_t)B * 128;
    float* Wcat  = cbB  + (size_t)B * 128;
    float* WyT   = Wcat + 256 * 256;
    float* MT    = WyT  + 128 * 32;
    float* d0    = MT   + 128 * 32;

    setup_kernel<<<67, 256, 0, stream>>>(e_w1, s_xw, s_yw, s_temb, s_t1w, s_t1b,
                                         s_t2w, s_t2b, tr1w, tr1b, s_xb, s_yb,
                                         Wcat, WyT, MT, d0);
    rowpre_kernel<<<B / 64, 256, 0, stream>>>(x, tin, Wcat, e_b1, d0, hxeB, cbB);
    iterate_kernel<<<B / 256, 256, 0, stream>>>(hxeB, cbB, WyT, MT, e_w2, e_w3,
                                                tr2w, tr2b, e_b2, tin, steps,
                                                (float*)d_out);
}